// Round 3
// baseline (806.630 us; speedup 1.0000x reference)
//
#include <hip/hip_runtime.h>
#include <math.h>
#include <stdint.h>

// VQ nearest-codebook, round 3: pre-split bf16 operands + m97-style MFMA GEMM.
// dist = e2[k] - 2*dot; dot = xh*eh + xl*eh + xh*el as ONE K=768 bf16 GEMM
// (A row = [xh(256)|xl(256)] addressed [0,512)+[0,256); B row = [eh|eh|el]).
// Per-point top-2 tracked through the GEMM; exact fp32 recheck decides
// (scheme proven correct in round 2). Outputs (fp32): zq (N*256), idx (N).
// xs (bf16 split of x) lives in the zq region of d_out (exact size match);
// the final gather kernel overwrites it with zq after indices are decided.

typedef __attribute__((ext_vector_type(8))) short short8;   // 8 bf16 = 4 VGPR
typedef __attribute__((ext_vector_type(4))) float f32x4;

#define C_DIM 256

__device__ __forceinline__ unsigned short f2bf(float f) {
    unsigned u = __float_as_uint(f);
    return (unsigned short)((u + 0x7fffu + ((u >> 16) & 1u)) >> 16);
}
__device__ __forceinline__ float bf2f(unsigned short h) {
    return __uint_as_float((unsigned)h << 16);
}
__device__ __forceinline__ void gl_lds16(const void* g, void* l) {
    __builtin_amdgcn_global_load_lds((const __attribute__((address_space(1))) void*)g,
                                     (__attribute__((address_space(3))) void*)l, 16, 0, 0);
}

// x (N x 256 fp32) -> xs (N x 512 bf16): [xh | xl]. 16 elems/thread.
__global__ __launch_bounds__(256) void vq_prep_x(const float* __restrict__ x,
                                                 uint16_t* __restrict__ xs, int N) {
    int gid = blockIdx.x * 256 + threadIdx.x;
    int p = gid >> 4;
    int c0 = (gid & 15) << 4;
    if (p >= N) return;
    const float4* src = (const float4*)(x + (size_t)p * C_DIM + c0);
    uint16_t hbuf[16], lbuf[16];
#pragma unroll
    for (int i = 0; i < 4; ++i) {
        float4 v = src[i];
        float vv[4] = {v.x, v.y, v.z, v.w};
#pragma unroll
        for (int j = 0; j < 4; ++j) {
            unsigned short h = f2bf(vv[j]);
            hbuf[i * 4 + j] = h;
            lbuf[i * 4 + j] = f2bf(vv[j] - bf2f(h));
        }
    }
    uint16_t* dh = xs + (size_t)p * 512 + c0;
    uint16_t* dl = dh + 256;
    ((int4*)dh)[0] = ((const int4*)hbuf)[0];
    ((int4*)dh)[1] = ((const int4*)hbuf)[1];
    ((int4*)dl)[0] = ((const int4*)lbuf)[0];
    ((int4*)dl)[1] = ((const int4*)lbuf)[1];
}

// cb (K x 256 fp32) -> cbs (K x 768 bf16): [eh | eh | el], plus exact fp32 e2.
__global__ __launch_bounds__(256) void vq_prep_cb(const float* __restrict__ cb,
                                                  uint16_t* __restrict__ cbs,
                                                  float* __restrict__ e2, int K) {
    int w = threadIdx.x >> 6, lane = threadIdx.x & 63;
    int code = blockIdx.x * 4 + w;
    if (code >= K) return;
    float4 v = ((const float4*)(cb + (size_t)code * C_DIM))[lane];
    float vv[4] = {v.x, v.y, v.z, v.w};
    uint16_t eh[4], el[4];
#pragma unroll
    for (int j = 0; j < 4; ++j) {
        eh[j] = f2bf(vv[j]);
        el[j] = f2bf(vv[j] - bf2f(eh[j]));
    }
    uint16_t* row = cbs + (size_t)code * 768;
    *(int2*)(row + lane * 4)       = *(const int2*)eh;
    *(int2*)(row + 256 + lane * 4) = *(const int2*)eh;
    *(int2*)(row + 512 + lane * 4) = *(const int2*)el;
    float s = vv[0] * vv[0] + vv[1] * vv[1] + vv[2] * vv[2] + vv[3] * vv[3];
#pragma unroll
    for (int off = 32; off > 0; off >>= 1) s += __shfl_down(s, off, 64);
    if (lane == 0) e2[code] = s;
}

// Main: 128 pts x 128 codes per (block, kt), K-loop 12 steps of BK=64.
// LDS 2x16KB, XOR-swizzled chunks (2-way conflicts only = free).
// Writes 2 candidate codes per point to cand[].
__global__ __launch_bounds__(256, 3) void vq_mfma(
    const uint16_t* __restrict__ xs, const uint16_t* __restrict__ cbs,
    const float* __restrict__ e2, int* __restrict__ cand, int ktn) {

    __shared__ uint16_t sA[128 * 64];
    __shared__ uint16_t sB[128 * 64];

    const int tid = threadIdx.x;
    const int lane = tid & 63;
    const int w = tid >> 6;
    const int ln = lane & 15;
    const int q = lane >> 4;
    const int wm = (w & 1) * 64;
    const int wn = (w >> 1) * 64;
    const size_t basep = (size_t)blockIdx.x * 128;

    const int r0 = w * 8 + (lane >> 3);            // staging row for load i: r0+i*32
    const int gsw = (lane & 7) ^ (r0 & 7);         // swizzled source chunk

    int offAB[2][4];                               // frag-read byte offsets (A); B adds bAdd
#pragma unroll
    for (int h = 0; h < 2; ++h)
#pragma unroll
        for (int mt = 0; mt < 4; ++mt) {
            int R = wm + mt * 16 + ln;
            offAB[h][mt] = R * 128 + (((h * 4 + q) ^ (R & 7)) * 16);
        }
    const int bAdd = (wn - wm) * 128;

    float d1s[16], d2s[16];
    int c12[16];                                   // c1 | c2<<16
#pragma unroll
    for (int s = 0; s < 16; ++s) { d1s[s] = 1e30f; d2s[s] = 1e30f; c12[s] = 0x00010000; }

    for (int kt = 0; kt < ktn; ++kt) {
        f32x4 acc[4][4];
#pragma unroll
        for (int mt = 0; mt < 4; ++mt)
#pragma unroll
            for (int nt = 0; nt < 4; ++nt)
#pragma unroll
                for (int r = 0; r < 4; ++r) acc[mt][nt][r] = 0.0f;

        float e2v[4];
#pragma unroll
        for (int nt = 0; nt < 4; ++nt) e2v[nt] = e2[kt * 128 + wn + nt * 16 + ln];

        const uint16_t* aBase = xs + (basep + r0) * 512 + gsw * 8;
        const uint16_t* bBase = cbs + (size_t)(kt * 128 + r0) * 768 + gsw * 8;

        for (int kk = 0; kk < 12; ++kk) {
            const int segA = kk * 64 - (kk >= 8 ? 512 : 0);  // [xh|xl|xh]
            const int segB = kk * 64;                        // [eh|eh|el]
            __syncthreads();
#pragma unroll
            for (int i = 0; i < 4; ++i)
                gl_lds16(aBase + i * (32 * 512) + segA, (char*)sA + i * 4096 + w * 1024);
#pragma unroll
            for (int i = 0; i < 4; ++i)
                gl_lds16(bBase + i * (32 * 768) + segB, (char*)sB + i * 4096 + w * 1024);
            __syncthreads();

#pragma unroll
            for (int h = 0; h < 2; ++h) {
                short8 af[4], bfr[4];
#pragma unroll
                for (int j = 0; j < 4; ++j) {
                    af[j]  = *(const short8*)((const char*)sA + offAB[h][j]);
                    bfr[j] = *(const short8*)((const char*)sB + offAB[h][j] + bAdd);
                }
#pragma unroll
                for (int mt = 0; mt < 4; ++mt)
#pragma unroll
                    for (int nt = 0; nt < 4; ++nt)
                        acc[mt][nt] = __builtin_amdgcn_mfma_f32_16x16x32_bf16(
                            af[mt], bfr[nt], acc[mt][nt], 0, 0, 0);
            }
        }

        const int cnB = kt * 128 + wn + ln;
#pragma unroll
        for (int mt = 0; mt < 4; ++mt)
#pragma unroll
            for (int r = 0; r < 4; ++r) {
                int s = mt * 4 + r;
                float d0 = fmaf(-2.f, acc[mt][0][r], e2v[0]);
                float d1 = fmaf(-2.f, acc[mt][1][r], e2v[1]);
                float d2 = fmaf(-2.f, acc[mt][2][r], e2v[2]);
                float d3 = fmaf(-2.f, acc[mt][3][r], e2v[3]);
                int cn0 = cnB, cn1 = cnB + 16, cn2 = cnB + 32, cn3 = cnB + 48;
                bool s01 = d1 < d0;
                float lo0 = s01 ? d1 : d0, hi0 = s01 ? d0 : d1;
                int lc0 = s01 ? cn1 : cn0, hc0 = s01 ? cn0 : cn1;
                bool s23 = d3 < d2;
                float lo1 = s23 ? d3 : d2, hi1 = s23 ? d2 : d3;
                int lc1 = s23 ? cn3 : cn2, hc1 = s23 ? cn2 : cn3;
                bool sw = lo1 < lo0;
                float b1 = sw ? lo1 : lo0; int b1c = sw ? lc1 : lc0;
                float ca = sw ? lo0 : lo1; int cac = sw ? lc0 : lc1;
                float cb2 = sw ? hi1 : hi0; int cbc = sw ? hc1 : hc0;
                bool t2 = cb2 < ca;
                float m2 = t2 ? cb2 : ca; int m2c = t2 ? cbc : cac;
                float rr1 = d1s[s], rr2 = d2s[s];
                int pc = c12[s];
                int rc1 = pc & 0xffff, rc2 = (int)(((unsigned)pc) >> 16);
                bool l1 = b1 < rr1;
                bool l2 = b1 < rr2;
                bool mlt = m2 < rr1;
                float n1 = l1 ? b1 : rr1;
                int nc1 = l1 ? b1c : rc1;
                float n2 = l1 ? (mlt ? m2 : rr1) : (l2 ? b1 : rr2);
                int nc2 = l1 ? (mlt ? m2c : rc1) : (l2 ? b1c : rc2);
                d1s[s] = n1; d2s[s] = n2;
                c12[s] = nc1 | (nc2 << 16);
            }
    }

#pragma unroll
    for (int m = 1; m <= 8; m <<= 1) {
#pragma unroll
        for (int s = 0; s < 16; ++s) {
            float od1 = __shfl_xor(d1s[s], m);
            float od2 = __shfl_xor(d2s[s], m);
            int opc = __shfl_xor(c12[s], m);
            int oc1 = opc & 0xffff, oc2 = (int)(((unsigned)opc) >> 16);
            int c1 = c12[s] & 0xffff, c2 = (int)(((unsigned)c12[s]) >> 16);
            float d1v = d1s[s], d2v = d2s[s];
            bool t = (od1 < d1v) || (od1 == d1v && oc1 < c1);
            float hd = t ? d1v : od1;  int hc = t ? c1 : oc1;
            float nd1 = t ? od1 : d1v; int nc1 = t ? oc1 : c1;
            bool u = (od2 < d2v) || (od2 == d2v && oc2 < c2);
            float md = u ? od2 : d2v;  int mc = u ? oc2 : c2;
            bool v2 = (hd < md) || (hd == md && hc < mc);
            d1s[s] = nd1;
            d2s[s] = v2 ? hd : md;
            c12[s] = nc1 | ((v2 ? hc : mc) << 16);
        }
    }

    __syncthreads();
    float* mD1 = (float*)sA;
    int*   mC1 = (int*)sA + 256;
    float* mD2 = (float*)sA + 512;
    int*   mC2 = (int*)sA + 768;

    if (ln == 0) {
        int half = w >> 1;
#pragma unroll
        for (int mt = 0; mt < 4; ++mt)
#pragma unroll
            for (int r = 0; r < 4; ++r) {
                int s = mt * 4 + r;
                int p = wm + mt * 16 + q * 4 + r;
                mD1[p * 2 + half] = d1s[s];
                mC1[p * 2 + half] = c12[s] & 0xffff;
                mD2[p * 2 + half] = d2s[s];
                mC2[p * 2 + half] = (int)(((unsigned)c12[s]) >> 16);
            }
    }
    __syncthreads();

    if (tid < 128) {
        float da1 = mD1[tid * 2], db1 = mD1[tid * 2 + 1];
        int ca1 = mC1[tid * 2], cb1i = mC1[tid * 2 + 1];
        float da2 = mD2[tid * 2], db2 = mD2[tid * 2 + 1];
        int ca2 = mC2[tid * 2], cb2i = mC2[tid * 2 + 1];
        bool t = (db1 < da1) || (db1 == da1 && cb1i < ca1);
        int c1f = t ? cb1i : ca1;
        float xd1 = t ? db2 : da2;
        int xc1 = t ? cb2i : ca2;
        float xd2 = t ? da1 : db1;
        int xc2 = t ? ca1 : cb1i;
        bool u = (xd1 < xd2) || (xd1 == xd2 && xc1 < xc2);
        int c2f = u ? xc1 : xc2;
        cand[(basep + tid) * 2]     = c1f;
        cand[(basep + tid) * 2 + 1] = c2f;
    }
}

// exact fp32 recheck: thread pair per point; writes final index (as float)
__global__ __launch_bounds__(256) void vq_recheck(
    const float* __restrict__ x, const float* __restrict__ cb,
    const float* __restrict__ e2, const int* __restrict__ cand,
    float* __restrict__ idxf, int N) {
    int gid = blockIdx.x * 256 + threadIdx.x;   // 2*N threads
    int p = gid >> 1;
    if (p >= N) return;
    int cc = cand[gid];
    const float4* xr4 = (const float4*)(x + (size_t)p * C_DIM);
    const float4* cr4 = (const float4*)(cb + (size_t)cc * C_DIM);
    float4 s4 = {0.f, 0.f, 0.f, 0.f};
#pragma unroll 8
    for (int j = 0; j < 64; ++j) {
        float4 a = xr4[j], b = cr4[j];
        s4.x = fmaf(a.x, b.x, s4.x);
        s4.y = fmaf(a.y, b.y, s4.y);
        s4.z = fmaf(a.z, b.z, s4.z);
        s4.w = fmaf(a.w, b.w, s4.w);
    }
    float dot = (s4.x + s4.y) + (s4.z + s4.w);
    float d = fmaf(-2.0f, dot, e2[cc]);
    float od = __shfl_xor(d, 1);
    int oc = __shfl_xor(cc, 1);
    int winc = (d < od || (d == od && cc < oc)) ? cc : oc;
    if ((gid & 1) == 0) idxf[p] = (float)winc;
}

// gather: zq[p] = cb[idx[p]]; one wave per point (overwrites the xs region)
__global__ __launch_bounds__(256) void vq_gather(const float* __restrict__ cb,
                                                 const float* __restrict__ idxf,
                                                 float* __restrict__ zq, int N) {
    int wv = threadIdx.x >> 6, lane = threadIdx.x & 63;
    size_t p = (size_t)blockIdx.x * 4 + wv;
    if (p >= (size_t)N) return;
    int c = (int)idxf[p];
    float4 v = ((const float4*)(cb + (size_t)c * C_DIM))[lane];
    ((float4*)(zq + p * C_DIM))[lane] = v;
}

extern "C" void kernel_launch(void* const* d_in, const int* in_sizes, int n_in,
                              void* d_out, int out_size, void* d_ws, size_t ws_size,
                              hipStream_t stream) {
    const float* x = (const float*)d_in[0];
    const float* cb = (const float*)d_in[1];
    int N = in_sizes[0] / C_DIM;   // 131072
    int K = in_sizes[1] / C_DIM;   // 1024

    float* zq = (float*)d_out;
    float* idxf = zq + (size_t)N * C_DIM;
    uint16_t* xs = (uint16_t*)d_out;                    // aliases zq region (exact fit)
    uint16_t* cbs = (uint16_t*)d_ws;                    // K*768 bf16 = 1.5 MB
    float* e2 = (float*)((char*)d_ws + (size_t)K * 768 * 2);
    int* cand = (int*)(e2 + K);                         // 2*N ints = 1 MB

    vq_prep_cb<<<dim3(K / 4), 256, 0, stream>>>(cb, cbs, e2, K);
    vq_prep_x<<<dim3(N / 16), 256, 0, stream>>>(x, xs, N);
    vq_mfma<<<dim3(N / 128), 256, 0, stream>>>(xs, cbs, e2, cand, K / 128);
    vq_recheck<<<dim3((2 * N + 255) / 256), 256, 0, stream>>>(x, cb, e2, cand, idxf, N);
    vq_gather<<<dim3((N + 3) / 4), 256, 0, stream>>>(cb, idxf, zq, N);
}